// Round 5
// baseline (124.992 us; speedup 1.0000x reference)
//
#include <hip/hip_runtime.h>
#include <hip/hip_bf16.h>

// out[b,i] = sum_{j<=i} x[b,j] * kernel[i-j]   (causal Toeplitz matmul)
// M=2048, N=K=4096. f32 in/out, bf16 MFMA compute.
//
// R10: self-synced A pipeline. R9 showed the kernel is stall-bound (MfmaUtil
// 27 + VALU 13 -> 60% idle): per-step barrier + 2-deep buffers force all 16
// waves to burst reads then burst MFMAs (port 3.1K + matrix 2.5K run SERIAL,
// wall 6.4K cyc/CU-step). Now: K=32 half-steps, A in 3 rotating 8KB/group
// buffers (fits: A 48K + B 14.6K = 63.7KB, 2 blocks/CU). Each wave stages ALL
// 64 rows it consumes (wn-partners duplicate-write identical bytes - benign),
// so A publication = own counted vmcnt (4 or 5, never 0 midloop): waves
// self-pace, reads of one wave overlap MFMAs of another. s_barrier only every
// 2 half-steps (bounds skew; 3-buf rotation keeps writers >=2 steps from any
// reader; B chunk publication rides the same barrier after the vmcnt gate).
// A-read swizzle: 128B lines hold 2 rows x 4 16B-units, unit' = unit^(line&7);
// gll stages linearly with the inverse swizzle applied to the GLOBAL source
// (both-sides rule). B machinery (8 shifted krev copies) unchanged; R9's
// counter identity (conflicts 2.16M with A reads removed) proved A-path is
// conflict-free and all conflicts are B (+4cyc/read, left for later).

typedef unsigned short u16;
typedef __attribute__((ext_vector_type(8))) short  bf16x8;
typedef __attribute__((ext_vector_type(8))) unsigned short u16x8;
typedef __attribute__((ext_vector_type(4))) float  f32x4;

#define KDIM 4096
#define NDIM 4096
#define MDIM 2048
#define KREV_STRIDE 4608                    // elems per shifted copy
#define KREV_BYTES  (8 * KREV_STRIDE * 2)   // 73728
#define BSTRIDE 456                         // LDS B copy stride (elems); reads use [1,391)
#define BBUF    (8 * BSTRIDE)               // 3648 elems per B buffer
#define ABUFS   49152                       // 3 bufs x 2 groups x 8192 B

#define MFMA_BF16 __builtin_amdgcn_mfma_f32_16x16x32_bf16

static __device__ inline u16 f2bf(float f) {
  unsigned u = __builtin_bit_cast(unsigned, f);
  unsigned r = u + 0x7FFFu + ((u >> 16) & 1u);
  return (u16)(r >> 16);
}

static __device__ inline void async_copy16(const void* g, void* l) {
  __builtin_amdgcn_global_load_lds((const __attribute__((address_space(1))) void*)g,
                                   (__attribute__((address_space(3))) void*)l,
                                   16, 0, 0);
}

// Fused prep: blocks [0, conv_blocks) convert x->bf16 row-major; last 18
// blocks build 8 shifted krev copies. krevs[a][u] = krev_logical[u+a-8];
// krev_logical[t] = kern[4095-t] for t in [0,4096) else 0.
__global__ __launch_bounds__(256) void prep(const float* __restrict__ x,
                                            const float* __restrict__ kern,
                                            u16* __restrict__ xb,
                                            u16* __restrict__ krevs,
                                            int conv_blocks) {
  int kb = (int)blockIdx.x - conv_blocks;
  if (kb >= 0) {
    int u = kb * 256 + threadIdx.x;
    for (int a = 0; a < 8; ++a) {
      int t = u + a - 8;
      u16 v = 0;
      if (t >= 0 && t <= 4095) v = f2bf(kern[4095 - t]);
      krevs[a * KREV_STRIDE + u] = v;
    }
  } else {
    size_t i = ((size_t)blockIdx.x * 256 + threadIdx.x) * 8;
    const f32x4* p = (const f32x4*)(x + i);
    f32x4 v0 = p[0], v1 = p[1];
    u16x8 r;
    r[0] = f2bf(v0[0]); r[1] = f2bf(v0[1]); r[2] = f2bf(v0[2]); r[3] = f2bf(v0[3]);
    r[4] = f2bf(v1[0]); r[5] = f2bf(v1[1]); r[6] = f2bf(v1[2]); r[7] = f2bf(v1[3]);
    *(u16x8*)(xb + i) = r;
  }
}

template <bool CONV>
__global__ __launch_bounds__(512, 4) void toeplitz_gemm(const void* __restrict__ Av,
                                                        const u16* __restrict__ krevs,
                                                        float* __restrict__ out) {
  // LDS: A 3 rotating bufs x 2 groups x 8192 B = 49152, B 2 x 3648 elems =
  // 14592 -> 63744 B total (2 blocks/CU). Epilogue overlay needs 36864 B.
  __shared__ __align__(16) char smem_raw[63744];
  u16*   B_all = (u16*)(smem_raw + ABUFS);
  f32x4* ep    = (f32x4*)smem_raw;            // epilogue overlay, 9 f32x4 per slot

  const int tid  = threadIdx.x;
  const int w    = tid >> 6;        // 0..7
  const int g    = w >> 2;          // K-group 0..1 (K=32 slices now)
  const int wl   = w & 3;           // wave-in-group
  const int lane = tid & 63;
  const int lane16 = lane & 15;
  const int quad   = lane >> 4;
  const int wm = wl >> 1;
  const int wn = wl & 1;

  // XCD-affine, balance-correct mapping (R8): XCD x_=b&7 owns m-panels
  // {x_,x_+8}; co-resident pair (b, b+256) shares one panel, ct sum = 31.
  const int b  = (int)blockIdx.x;
  const int x_ = b & 7;
  const int jj = b >> 3;                  // 0..63 within XCD
  const int q  = jj & 31;
  const int h2 = jj >> 5;
  const int mt = x_ + 8 * (q & 1);        // m-panel 0..15
  const int ct = h2 ? (q >> 1) : 31 - (q >> 1);
  const int n0 = ct * 128;
  const int m0 = mt * 128;
  const int W  = 3968 - n0;               // B window base for chunk 0
  const int hmax = 2 * ct + 1;            // half-steps 0..hmax (K=64 each, 32/group)
  const int cmax = ct >> 1;               // last B chunk index

  // B frag: elem j = krev_logical[s0 + k], s0 = 4095-n_g+quad*8; chunk c holds
  // krev_logical[W + c*256 + u + a - 8] at copy a elem u (u in [0,448)).
  int boff[4];
  for (int fn = 0; fn < 4; ++fn) {
    int n_g = n0 + wn * 64 + fn * 16 + lane16;
    int s0  = 4095 - n_g + quad * 8;
    int a   = s0 & 7;
    boff[fn] = a * BSTRIDE + (s0 - a + 8 - W);
  }

  f32x4 acc[4][4] = {};

  // A swizzle: per group-buf (8KB = 128 rows x 32 k), 128B line L holds rows
  // {2L, 2L+1} as 8 16B-units u (u = (row&1)*4 + kunit), stored at unit
  // u' = u ^ (L&7). Staging writes linearly (gll: lane l -> byte l*16 of a
  // 1KB block = line l>>3, unit l&7); the swizzle is applied to the SOURCE:
  const int u_   = (lane & 7) ^ ((lane >> 3) & 7);
  const int srow = 2 * (lane >> 3) + (u_ >> 2);   // row within 16-row chunk
  const int skof = (u_ & 3) * 8;                  // k offset within 32
  // A fragment read offset (bytes within group-buf):
  const int aoff = wm * 4096 + (lane16 >> 1) * 128 +
                   ((((lane16 & 1) << 2) | quad) ^ (lane16 >> 1)) * 16;

  const u16*   xb = (const u16*)Av;
  const float* xf = (const float*)Av;
  char* Agrp = smem_raw + g * 8192;       // + s*16384 selects rotation slot

  // per-lane global source base (row-major xb), k advances 64/half-step
  const u16* srcbase = xb + (size_t)(m0 + wm * 64 + srow) * KDIM + g * 32 + skof;

  auto stageA = [&](int hh, int ss) {     // FAST: 4 gll of 1KB, dup across wn
    char* dst = Agrp + ss * 16384 + wm * 4096;
    const u16* sp = srcbase + (size_t)hh * 64;
    for (int c = 0; c < 4; ++c)
      async_copy16(sp + (size_t)c * 16 * KDIM, dst + c * 1024);
  };
  auto stageA_conv = [&](int hh, int ss) { // CONV: VALU convert + ds_write
    char* dst = Agrp + ss * 16384 + wm * 4096;
    for (int c = 0; c < 4; ++c) {
      const float* px = xf + (size_t)(m0 + wm * 64 + c * 16 + srow) * KDIM +
                        (size_t)hh * 64 + g * 32 + skof;
      f32x4 v0 = *(const f32x4*)px, v1 = *(const f32x4*)(px + 4);
      u16x8 r;
      r[0]=f2bf(v0[0]); r[1]=f2bf(v0[1]); r[2]=f2bf(v0[2]); r[3]=f2bf(v0[3]);
      r[4]=f2bf(v1[0]); r[5]=f2bf(v1[1]); r[6]=f2bf(v1[2]); r[7]=f2bf(v1[3]);
      *(u16x8*)(dst + c * 1024 + lane * 16) = r;
    }
  };
  auto stageB = [&](int c) {               // 8 waves x 56 lanes: 448 elems/copy
    if (lane < 56)
      async_copy16(krevs + w * KREV_STRIDE + W + c * 256 + (lane << 3),
                   &B_all[(c & 1) * BBUF + w * BSTRIDE]);
  };

  auto compute = [&](int hh, int ss) {
    const u16* Bb  = B_all + ((hh >> 2) & 1) * BBUF;
    const int bofs = (hh & 3) * 64 + g * 32;
    const char* Ab = Agrp + ss * 16384;
    bf16x8 af[4], bfr[4];
    for (int fm = 0; fm < 4; ++fm)
      af[fm] = *(const bf16x8*)(Ab + aoff + fm * 1024);
    for (int fn = 0; fn < 4; ++fn)
      bfr[fn] = *(const bf16x8*)(&Bb[boff[fn] + bofs]);
    for (int fm = 0; fm < 4; ++fm)
      for (int fn = 0; fn < 4; ++fn)
        acc[fm][fn] = MFMA_BF16(af[fm], bfr[fn], acc[fm][fn], 0, 0, 0);
  };

  int s = 0, sw = 1;
  if constexpr (!CONV) {
    // prologue
    stageB(0);
    stageA(0, 0);
    asm volatile("s_waitcnt vmcnt(0)" ::: "memory");
    __builtin_amdgcn_s_barrier();
    asm volatile("" ::: "memory");
    for (int h = 0; ; ++h) {
      // issue order matters for the vmcnt gate: B first, then A(h+1)
      int nleft = 0;
      if ((h & 3) == 0 && (h >> 2) + 1 <= cmax) { stageB((h >> 2) + 1); nleft += 1; }
      if (h + 1 <= hmax) { stageA(h + 1, sw); nleft += 4; }
      // gate: drain own A(h) (issued last half-step); leave newest nleft.
      if (nleft == 5)      asm volatile("s_waitcnt vmcnt(5)" ::: "memory");
      else if (nleft == 4) asm volatile("s_waitcnt vmcnt(4)" ::: "memory");
      else                 asm volatile("s_waitcnt vmcnt(0)" ::: "memory");
      compute(h, s);
      if (h == hmax) break;
      if (h & 1) {   // window boundary: bound skew, publish B chunk
        asm volatile("" ::: "memory");
        __builtin_amdgcn_s_barrier();
        asm volatile("" ::: "memory");
      }
      s = sw; sw = (sw == 2) ? 0 : sw + 1;
    }
  } else {
    // CONV fallback: simple per-half-step syncthreads pipeline
    stageB(0);
    stageA_conv(0, 0);
    __syncthreads();
    for (int h = 0; ; ++h) {
      if ((h & 3) == 0 && (h >> 2) + 1 <= cmax) stageB((h >> 2) + 1);
      compute(h, s);
      if (h < hmax) stageA_conv(h + 1, sw);
      if (h == hmax) break;
      __syncthreads();
      s = sw; sw = (sw == 2) ? 0 : sw + 1;
    }
  }

  // combine: group1's partials -> group0 via LDS (2 rounds of 2 fm each)
  const int j = tid & 255;
  for (int r = 0; r < 2; ++r) {
    __syncthreads();                       // (r=0: also fences last compute reads)
    if (g == 1) {
      for (int fm2 = 0; fm2 < 2; ++fm2)
        for (int fn = 0; fn < 4; ++fn)
          ep[j * 9 + fm2 * 4 + fn] = acc[r * 2 + fm2][fn];
    }
    __syncthreads();
    if (g == 0) {
      for (int fm2 = 0; fm2 < 2; ++fm2)
        for (int fn = 0; fn < 4; ++fn)
          acc[r * 2 + fm2][fn] += ep[j * 9 + fm2 * 4 + fn];
    }
  }

  // epilogue (group 0 only): C/D layout col=lane&15, row=quad*4+r
  if (g == 0) {
    for (int fm = 0; fm < 4; ++fm) {
      int row_base = m0 + wm * 64 + fm * 16 + quad * 4;
      for (int fn = 0; fn < 4; ++fn) {
        int col = n0 + wn * 64 + fn * 16 + lane16;
        for (int r = 0; r < 4; ++r)
          out[(size_t)(row_base + r) * NDIM + col] = acc[fm][fn][r];
      }
    }
  }
}

extern "C" void kernel_launch(void* const* d_in, const int* in_sizes, int n_in,
                              void* d_out, int out_size, void* d_ws, size_t ws_size,
                              hipStream_t stream) {
  const float* x    = (const float*)d_in[0];
  const float* kern = (const float*)d_in[1];
  float* out = (float*)d_out;

  u16* krevs = (u16*)d_ws;
  u16* xb    = (u16*)((char*)d_ws + KREV_BYTES);
  const size_t need_fast = (size_t)KREV_BYTES + (size_t)MDIM * KDIM * 2;

  if (ws_size >= need_fast) {
    prep<<<4096 + 18, 256, 0, stream>>>(x, kern, xb, krevs, 4096);
    toeplitz_gemm<false><<<512, 512, 0, stream>>>(xb, krevs, out);
  } else {
    prep<<<18, 256, 0, stream>>>(x, kern, xb, krevs, 0);
    toeplitz_gemm<true><<<512, 512, 0, stream>>>(x, krevs, out);
  }
}

// Round 6
// 122.155 us; speedup vs baseline: 1.0232x; 1.0232x over previous
//
#include <hip/hip_runtime.h>
#include <hip/hip_bf16.h>

// out[b,i] = sum_{j<=i} x[b,j] * kernel[i-j]   (causal Toeplitz matmul)
// M=2048, N=K=4096. f32 in/out, bf16 MFMA compute.
//
// R11: A direct from L2 into REGISTERS with 1-step prefetch; B stays in LDS.
// Evidence: R8/R9/R10 all plateau 43-50us with port(3.1K)+matrix(2.5K) cyc
// per CU pair-step running serial; SQ_LDS_BANK_CONFLICT constant 2.16M =
// +4cyc x 64 B-reads/block-step (A path conflict-free). A in LDS is 2x the
// port traffic for zero reuse benefit (panels are L2-resident by the R8 XCD
// mapping). R9 proved A-from-global correct but stalled (JIT loads exposed
// L2 latency). Fix: afA/afB named register sets, loads for step t+1 issued
// right after the consuming MFMAs of step t (~2400cyc hiding vs ~400 L2
// latency; compiler emits counted vmcnt). LDS port demand drops to 64
// B-reads/pair-step (0.8K cyc << 2.5K matrix). Barrier only at B-chunk
// boundaries (every 2 steps), publication guarded by vmcnt(12) (loads issued
// after the stageB gll) - never vmcnt(0) midloop. B-frag reads JIT per-fn,
// A addressing SGPR-ized (readfirstlane) to hold ~124 total regs, 4 w/SIMD.

typedef unsigned short u16;
typedef __attribute__((ext_vector_type(8))) short  bf16x8;
typedef __attribute__((ext_vector_type(8))) unsigned short u16x8;
typedef __attribute__((ext_vector_type(4))) float  f32x4;

#define KDIM 4096
#define NDIM 4096
#define MDIM 2048
#define KREV_STRIDE 4608                    // elems per shifted copy
#define KREV_BYTES  (8 * KREV_STRIDE * 2)   // 73728
#define BSTRIDE 456                         // LDS B copy stride (elems)
#define BBUF    (8 * BSTRIDE)               // 3648 elems per B buffer

#define MFMA_BF16 __builtin_amdgcn_mfma_f32_16x16x32_bf16

static __device__ inline u16 f2bf(float f) {
  unsigned u = __builtin_bit_cast(unsigned, f);
  unsigned r = u + 0x7FFFu + ((u >> 16) & 1u);
  return (u16)(r >> 16);
}

static __device__ inline void async_copy16(const void* g, void* l) {
  __builtin_amdgcn_global_load_lds((const __attribute__((address_space(1))) void*)g,
                                   (__attribute__((address_space(3))) void*)l,
                                   16, 0, 0);
}

// Fused prep: blocks [0, conv_blocks) convert x->bf16 into the fragment-tiled
// layout; last 18 blocks build 8 shifted krev copies.
// Tiled layout: elem index = (rg*128 + kb)*512 + l*8 + e, where the 8 elems e
// are x[row = rg*16 + (l&15)][k = kb*32 + (l>>4)*8 + e]. One wave's fragment
// load (fixed rg,kb; l=lane) is 1KB contiguous.
__global__ __launch_bounds__(256) void prep(const float* __restrict__ x,
                                            const float* __restrict__ kern,
                                            u16* __restrict__ xb,
                                            u16* __restrict__ krevs,
                                            int conv_blocks) {
  int kblk = (int)blockIdx.x - conv_blocks;
  if (kblk >= 0) {
    int u = kblk * 256 + threadIdx.x;
    for (int a = 0; a < 8; ++a) {
      int t = u + a - 8;
      u16 v = 0;
      if (t >= 0 && t <= 4095) v = f2bf(kern[4095 - t]);
      krevs[a * KREV_STRIDE + u] = v;
    }
  } else {
    unsigned tg  = blockIdx.x * 256 + threadIdx.x;   // 0..2048*4096/8-1
    unsigned l   = tg & 63;
    unsigned kb  = (tg >> 6) & 127;
    unsigned rg  = tg >> 13;                         // 0..127
    unsigned row = rg * 16 + (l & 15);
    unsigned k   = kb * 32 + (l >> 4) * 8;
    const f32x4* p = (const f32x4*)(x + (size_t)row * KDIM + k);
    f32x4 v0 = p[0], v1 = p[1];
    u16x8 r;
    r[0] = f2bf(v0[0]); r[1] = f2bf(v0[1]); r[2] = f2bf(v0[2]); r[3] = f2bf(v0[3]);
    r[4] = f2bf(v1[0]); r[5] = f2bf(v1[1]); r[6] = f2bf(v1[2]); r[7] = f2bf(v1[3]);
    *(u16x8*)(xb + (size_t)tg * 8) = r;              // coalesced 1KB/wave
  }
}

template <bool CONV>
__global__ __launch_bounds__(512, 4) void toeplitz_gemm(const void* __restrict__ Av,
                                                        const u16* __restrict__ krevs,
                                                        float* __restrict__ out) {
  // LDS: B only, [2 bufs][8*456] = 14592 B, overlaid by 36864 B epilogue buf.
  __shared__ __align__(16) char smem_raw[36864];
  u16*   B_all = (u16*)smem_raw;
  f32x4* ep    = (f32x4*)smem_raw;            // epilogue overlay, 9 f32x4 per slot

  const int tid  = threadIdx.x;
  const int w    = tid >> 6;        // 0..7
  const int g    = w >> 2;          // K-group 0..1
  const int wl   = w & 3;           // wave-in-group
  const int lane = tid & 63;
  const int lane16 = lane & 15;
  const int quad   = lane >> 4;
  const int wm = wl >> 1;
  const int wn = wl & 1;

  // XCD-affine, balance-correct mapping (R8): XCD x_=b&7 owns m-panels
  // {x_,x_+8}; co-resident pair (b, b+256) shares one panel, ct sum = 31.
  const int b  = (int)blockIdx.x;
  const int x_ = b & 7;
  const int jj = b >> 3;                  // 0..63 within XCD
  const int q  = jj & 31;
  const int h2 = jj >> 5;
  const int mt = x_ + 8 * (q & 1);        // m-panel 0..15
  const int ct = h2 ? (q >> 1) : 31 - (q >> 1);
  const int n0 = ct * 128;
  const int m0 = mt * 128;
  const int W  = 3968 - n0;               // B window base for chunk 0
  const int cmax = ct >> 1;               // last B chunk index

  // B frag: elem j = krev_logical[s0 + k], s0 = 4095-n_g+quad*8; chunk c holds
  // krev_logical[W + c*256 + u + a - 8] at copy a elem u (u in [0,448)).
  int boff[4];
  for (int fn = 0; fn < 4; ++fn) {
    int n_g = n0 + wn * 64 + fn * 16 + lane16;
    int s0  = 4095 - n_g + quad * 8;
    int a   = s0 & 7;
    boff[fn] = a * BSTRIDE + (s0 - a + 8 - W);
  }

  f32x4 acc[4][4] = {};

  // A addressing: SGPR-ize the wave-uniform parts so the loads compile to
  // saddr + 32-bit voffset (4 VGPR total). elem(fm,t,kk) =
  // (mt*8 + wm*4 + fm)*65536 + g*1024 + t*2048 + kk*512 + lane*8.
  const int wmu = __builtin_amdgcn_readfirstlane(wm);
  const int gu  = __builtin_amdgcn_readfirstlane(g);
  const u16*   xb2 = (const u16*)Av;
  const float* xf  = (const float*)Av;
  int aoffs[4];
  for (int fm = 0; fm < 4; ++fm)
    aoffs[fm] = (mt * 8 + wmu * 4 + fm) * 65536 + gu * 1024 + lane * 8;
  const int rowb = m0 + wm * 64 + lane16;   // CONV source row base

  auto ldA = [&](int fm, int t, int kk) -> bf16x8 {
    return *(const bf16x8*)(xb2 + aoffs[fm] + t * 2048 + kk * 512);
  };
  auto ldAc = [&](int fm, int t, int kk) -> bf16x8 {
    const float* px = xf + (size_t)(rowb + fm * 16) * KDIM +
                      t * 128 + gu * 64 + kk * 32 + quad * 8;
    f32x4 v0 = *(const f32x4*)px, v1 = *(const f32x4*)(px + 4);
    u16x8 r;
    r[0]=f2bf(v0[0]); r[1]=f2bf(v0[1]); r[2]=f2bf(v0[2]); r[3]=f2bf(v0[3]);
    r[4]=f2bf(v1[0]); r[5]=f2bf(v1[1]); r[6]=f2bf(v1[2]); r[7]=f2bf(v1[3]);
    return __builtin_bit_cast(bf16x8, r);
  };
  auto stageB = [&](int c) {               // 8 waves x 56 lanes: 448 elems/copy
    if (lane < 56)
      async_copy16(krevs + w * KREV_STRIDE + W + c * 256 + (lane << 3),
                   &B_all[(c & 1) * BBUF + w * BSTRIDE]);
  };

  if constexpr (!CONV) {
    bf16x8 afA[4], afB[4];
    // prologue: B chunk 0 staged; A(0,kk0/kk1) in flight
    stageB(0);
#pragma unroll
    for (int fm = 0; fm < 4; ++fm) afA[fm] = ldA(fm, 0, 0);
#pragma unroll
    for (int fm = 0; fm < 4; ++fm) afB[fm] = ldA(fm, 0, 1);
    asm volatile("s_waitcnt vmcnt(8)" ::: "memory");   // B(0) landed; af in flight
    __builtin_amdgcn_s_barrier();
    asm volatile("" ::: "memory");

    for (int t = 0; ; ++t) {
      const u16* Bb  = B_all + ((t >> 1) & 1) * BBUF;
      const int  ksl = (t & 1) * 128 + g * 64;
      // kk0: consume afA (compiler inserts counted vmcnt), B-frags JIT
#pragma unroll
      for (int fn = 0; fn < 4; ++fn) {
        bf16x8 bv = *(const bf16x8*)(&Bb[boff[fn] + ksl]);
#pragma unroll
        for (int fm = 0; fm < 4; ++fm)
          acc[fm][fn] = MFMA_BF16(afA[fm], bv, acc[fm][fn], 0, 0, 0);
      }
      if (t < ct)
#pragma unroll
        for (int fm = 0; fm < 4; ++fm) afA[fm] = ldA(fm, t + 1, 0);
      if (!(t & 1) && (t >> 1) + 1 <= cmax) stageB((t >> 1) + 1);
      // kk1: consume afB
#pragma unroll
      for (int fn = 0; fn < 4; ++fn) {
        bf16x8 bv = *(const bf16x8*)(&Bb[boff[fn] + ksl + 32]);
#pragma unroll
        for (int fm = 0; fm < 4; ++fm)
          acc[fm][fn] = MFMA_BF16(afB[fm], bv, acc[fm][fn], 0, 0, 0);
      }
      if (t < ct)
#pragma unroll
        for (int fm = 0; fm < 4; ++fm) afB[fm] = ldA(fm, t + 1, 1);
      if (t == ct) break;
      if (t & 1) {
        // publish B chunk staged at t-1: 12 loads issued after that gll
        // (afB(t-1) 4, afA(t) 4, afB(t) 4) -> vmcnt(12) guarantees it landed.
        asm volatile("s_waitcnt vmcnt(12)" ::: "memory");
        __builtin_amdgcn_s_barrier();
        asm volatile("" ::: "memory");
      }
    }
  } else {
    // CONV fallback: inline f32->bf16 A, per-chunk full drain (simple/correct)
    stageB(0);
    asm volatile("s_waitcnt vmcnt(0)" ::: "memory");
    __syncthreads();
    for (int t = 0; ; ++t) {
      const u16* Bb  = B_all + ((t >> 1) & 1) * BBUF;
      const int  ksl = (t & 1) * 128 + g * 64;
      if (!(t & 1) && (t >> 1) + 1 <= cmax) stageB((t >> 1) + 1);
#pragma unroll
      for (int kk = 0; kk < 2; ++kk) {
        bf16x8 af[4];
#pragma unroll
        for (int fm = 0; fm < 4; ++fm) af[fm] = ldAc(fm, t, kk);
#pragma unroll
        for (int fn = 0; fn < 4; ++fn) {
          bf16x8 bv = *(const bf16x8*)(&Bb[boff[fn] + ksl + kk * 32]);
#pragma unroll
          for (int fm = 0; fm < 4; ++fm)
            acc[fm][fn] = MFMA_BF16(af[fm], bv, acc[fm][fn], 0, 0, 0);
        }
      }
      if (t == ct) break;
      if (t & 1) {
        asm volatile("s_waitcnt vmcnt(0)" ::: "memory");
        __syncthreads();
      }
    }
  }

  // combine: group1's partials -> group0 via LDS (2 rounds of 2 fm each)
  const int j = tid & 255;
  for (int r = 0; r < 2; ++r) {
    __syncthreads();                       // (r=0: also fences last compute reads)
    if (g == 1) {
      for (int fm2 = 0; fm2 < 2; ++fm2)
        for (int fn = 0; fn < 4; ++fn)
          ep[j * 9 + fm2 * 4 + fn] = acc[r * 2 + fm2][fn];
    }
    __syncthreads();
    if (g == 0) {
      for (int fm2 = 0; fm2 < 2; ++fm2)
        for (int fn = 0; fn < 4; ++fn)
          acc[r * 2 + fm2][fn] += ep[j * 9 + fm2 * 4 + fn];
    }
  }

  // epilogue (group 0 only): C/D layout col=lane&15, row=quad*4+r
  if (g == 0) {
    for (int fm = 0; fm < 4; ++fm) {
      int row_base = m0 + wm * 64 + fm * 16 + quad * 4;
      for (int fn = 0; fn < 4; ++fn) {
        int col = n0 + wn * 64 + fn * 16 + lane16;
        for (int r = 0; r < 4; ++r)
          out[(size_t)(row_base + r) * NDIM + col] = acc[fm][fn][r];
      }
    }
  }
}

extern "C" void kernel_launch(void* const* d_in, const int* in_sizes, int n_in,
                              void* d_out, int out_size, void* d_ws, size_t ws_size,
                              hipStream_t stream) {
  const float* x    = (const float*)d_in[0];
  const float* kern = (const float*)d_in[1];
  float* out = (float*)d_out;

  u16* krevs = (u16*)d_ws;
  u16* xb    = (u16*)((char*)d_ws + KREV_BYTES);
  const size_t need_fast = (size_t)KREV_BYTES + (size_t)MDIM * KDIM * 2;

  if (ws_size >= need_fast) {
    prep<<<4096 + 18, 256, 0, stream>>>(x, kern, xb, krevs, 4096);
    toeplitz_gemm<false><<<512, 512, 0, stream>>>(xb, krevs, out);
  } else {
    prep<<<18, 256, 0, stream>>>(x, kern, xb, krevs, 0);
    toeplitz_gemm<true><<<512, 512, 0, stream>>>(x, krevs, out);
  }
}

// Round 7
// 116.966 us; speedup vs baseline: 1.0686x; 1.0444x over previous
//
#include <hip/hip_runtime.h>
#include <hip/hip_bf16.h>

// out[b,i] = sum_{b,j<=i} x[b,j] * kernel[i-j]   (causal Toeplitz matmul)
// M=2048, N=K=4096. f32 in/out, bf16 MFMA compute.
//
// R12: barrier-free main loop. R8-R11 (five schedules: per-step barrier,
// direct-A, self-paced 3-buf, reg-prefetch A) ALL plateau at 43-50us =
// ~800 TF = the documented ceiling of barrier-cadenced 128-tile structures;
// MfmaUtil pinned at 26-28% regardless of port traffic or barrier count.
// The invariant is the rendezvous cadence itself. Fix exploitable only in
// THIS problem: B (krevs) is tiny -- a block's whole B window (8 shifted
// copies x full K range) is <= 68.7KB, fits in LDS next to nothing else
// (A is in registers since R11; 2x68.7KB keeps 2 blocks/CU). Stage ALL of B
// in the prologue (one vmcnt(0)+barrier), then the entire K loop runs with
// ZERO barriers / LDS writes / waitcnt gates: read-only LDS B + 1-step
// register-prefetched A from L2 (R8 XCD mapping keeps panels L2-resident).
// Copy stride = 128*(ct+1)+200 elems (== 8 mod 64) preserving the a*16B
// bank-phase spread of the old BSTRIDE=456 layout (conflict counter should
// stay ~2.16M as a control).

typedef unsigned short u16;
typedef __attribute__((ext_vector_type(8))) short  bf16x8;
typedef __attribute__((ext_vector_type(8))) unsigned short u16x8;
typedef __attribute__((ext_vector_type(4))) float  f32x4;

#define KDIM 4096
#define NDIM 4096
#define MDIM 2048
#define KREV_STRIDE 4608                    // elems per shifted copy (global)
#define KREV_BYTES  (8 * KREV_STRIDE * 2)   // 73728

#define MFMA_BF16 __builtin_amdgcn_mfma_f32_16x16x32_bf16

static __device__ inline u16 f2bf(float f) {
  unsigned u = __builtin_bit_cast(unsigned, f);
  unsigned r = u + 0x7FFFu + ((u >> 16) & 1u);
  return (u16)(r >> 16);
}

static __device__ inline void async_copy16(const void* g, void* l) {
  __builtin_amdgcn_global_load_lds((const __attribute__((address_space(1))) void*)g,
                                   (__attribute__((address_space(3))) void*)l,
                                   16, 0, 0);
}

// Fused prep: blocks [0, conv_blocks) convert x->bf16 into the fragment-tiled
// layout; last 18 blocks build 8 shifted krev copies.
// Tiled layout: elem index = (rg*128 + kb)*512 + l*8 + e, where the 8 elems e
// are x[row = rg*16 + (l&15)][k = kb*32 + (l>>4)*8 + e]. One wave's fragment
// load (fixed rg,kb; l=lane) is 1KB contiguous.
__global__ __launch_bounds__(256) void prep(const float* __restrict__ x,
                                            const float* __restrict__ kern,
                                            u16* __restrict__ xb,
                                            u16* __restrict__ krevs,
                                            int conv_blocks) {
  int kblk = (int)blockIdx.x - conv_blocks;
  if (kblk >= 0) {
    int u = kblk * 256 + threadIdx.x;
    for (int a = 0; a < 8; ++a) {
      int t = u + a - 8;
      u16 v = 0;
      if (t >= 0 && t <= 4095) v = f2bf(kern[4095 - t]);
      krevs[a * KREV_STRIDE + u] = v;
    }
  } else {
    unsigned tg  = blockIdx.x * 256 + threadIdx.x;   // 0..2048*4096/8-1
    unsigned l   = tg & 63;
    unsigned kb  = (tg >> 6) & 127;
    unsigned rg  = tg >> 13;                         // 0..127
    unsigned row = rg * 16 + (l & 15);
    unsigned k   = kb * 32 + (l >> 4) * 8;
    const f32x4* p = (const f32x4*)(x + (size_t)row * KDIM + k);
    f32x4 v0 = p[0], v1 = p[1];
    u16x8 r;
    r[0] = f2bf(v0[0]); r[1] = f2bf(v0[1]); r[2] = f2bf(v0[2]); r[3] = f2bf(v0[3]);
    r[4] = f2bf(v1[0]); r[5] = f2bf(v1[1]); r[6] = f2bf(v1[2]); r[7] = f2bf(v1[3]);
    *(u16x8*)(xb + (size_t)tg * 8) = r;              // coalesced 1KB/wave
  }
}

template <bool CONV>
__global__ __launch_bounds__(512, 4) void toeplitz_gemm(const void* __restrict__ Av,
                                                        const u16* __restrict__ krevs,
                                                        float* __restrict__ out) {
  // LDS: full B window, 8 copies x stride_e(ct) elems; max (ct=31):
  // 8 * (128*32+200) * 2 = 68736 B -> 2 blocks/CU (137.5KB <= 160KB).
  // Epilogue overlay needs 36864 B.
  __shared__ __align__(16) char smem_raw[68736];
  u16*   B_all = (u16*)smem_raw;
  f32x4* ep    = (f32x4*)smem_raw;            // epilogue overlay, 9 f32x4 per slot

  const int tid  = threadIdx.x;
  const int w    = tid >> 6;        // 0..7
  const int g    = w >> 2;          // K-group 0..1
  const int wl   = w & 3;           // wave-in-group
  const int lane = tid & 63;
  const int lane16 = lane & 15;
  const int quad   = lane >> 4;
  const int wm = wl >> 1;
  const int wn = wl & 1;

  // XCD-affine, balance-correct mapping (R8): XCD x_=b&7 owns m-panels
  // {x_,x_+8}; co-resident pair (b, b+256) shares one panel, ct sum = 31.
  const int b  = (int)blockIdx.x;
  const int x_ = b & 7;
  const int jj = b >> 3;                  // 0..63 within XCD
  const int q  = jj & 31;
  const int h2 = jj >> 5;
  const int mt = x_ + 8 * (q & 1);        // m-panel 0..15
  const int ct = h2 ? (q >> 1) : 31 - (q >> 1);
  const int n0 = ct * 128;
  const int m0 = mt * 128;
  const int W  = 3968 - n0;               // B window base

  // Whole-window B staging geometry. LDS copy a elem u = krevs[a][W+u] =
  // krev_logical[W+u+a-8]. Want krev_logical[s0+k] -> u = s0+k+8-a-W.
  // u range: u0 = s0-a+8-W in [1,159]; k up to 128*ct+96+7 -> LEN covers it.
  const int LEN_e    = 128 * (ct + 1) + 160;   // staged elems per copy
  const int stride_e = 128 * (ct + 1) + 200;   // == 8 mod 64: a*16B bank phase

  // B frag offsets: s0 = 4095-n_g+quad*8, a = s0&7.
  int boff[4];
  for (int fn = 0; fn < 4; ++fn) {
    int n_g = n0 + wn * 64 + fn * 16 + lane16;
    int s0  = 4095 - n_g + quad * 8;
    int a   = s0 & 7;
    boff[fn] = a * stride_e + (s0 - a + 8 - W);
  }

  f32x4 acc[4][4] = {};

  // A addressing (R11): SGPR-ized wave-uniform parts; elem(fm,t,kk) =
  // (mt*8 + wm*4 + fm)*65536 + g*1024 + t*2048 + kk*512 + lane*8.
  const int wmu = __builtin_amdgcn_readfirstlane(wm);
  const int gu  = __builtin_amdgcn_readfirstlane(g);
  const u16*   xb2 = (const u16*)Av;
  const float* xf  = (const float*)Av;
  int aoffs[4];
  for (int fm = 0; fm < 4; ++fm)
    aoffs[fm] = (mt * 8 + wmu * 4 + fm) * 65536 + gu * 1024 + lane * 8;
  const int rowb = m0 + wm * 64 + lane16;   // CONV source row base

  auto ldA = [&](int fm, int t, int kk) -> bf16x8 {
    return *(const bf16x8*)(xb2 + aoffs[fm] + t * 2048 + kk * 512);
  };
  auto ldAc = [&](int fm, int t, int kk) -> bf16x8 {
    const float* px = xf + (size_t)(rowb + fm * 16) * KDIM +
                      t * 128 + gu * 64 + kk * 32 + quad * 8;
    f32x4 v0 = *(const f32x4*)px, v1 = *(const f32x4*)(px + 4);
    u16x8 r;
    r[0]=f2bf(v0[0]); r[1]=f2bf(v0[1]); r[2]=f2bf(v0[2]); r[3]=f2bf(v0[3]);
    r[4]=f2bf(v1[0]); r[5]=f2bf(v1[1]); r[6]=f2bf(v1[2]); r[7]=f2bf(v1[3]);
    return __builtin_bit_cast(bf16x8, r);
  };

  // ---- prologue: stage the ENTIRE B window (wave w stages copy w) ----
  {
    const u16* src = krevs + w * KREV_STRIDE + W;
    char* dstb = smem_raw + (size_t)w * stride_e * 2;
    for (int c = 0; c * 512 < LEN_e; ++c) {
      int idx = c * 512 + lane * 8;
      if (idx < LEN_e)
        async_copy16(src + idx, dstb + (size_t)c * 1024);  // uniform base + lane*16
    }
  }
  asm volatile("s_waitcnt vmcnt(0)" ::: "memory");
  __builtin_amdgcn_s_barrier();
  asm volatile("" ::: "memory");

  // ---- main loop: ZERO barriers. Read-only LDS B + reg-prefetched A ----
  if constexpr (!CONV) {
    bf16x8 afA[4], afB[4];
#pragma unroll
    for (int fm = 0; fm < 4; ++fm) afA[fm] = ldA(fm, 0, 0);
#pragma unroll
    for (int fm = 0; fm < 4; ++fm) afB[fm] = ldA(fm, 0, 1);
    for (int t = 0; ; ++t) {
      const int ks = t * 128 + g * 64;
#pragma unroll
      for (int fn = 0; fn < 4; ++fn) {
        bf16x8 bv = *(const bf16x8*)(&B_all[boff[fn] + ks]);
#pragma unroll
        for (int fm = 0; fm < 4; ++fm)
          acc[fm][fn] = MFMA_BF16(afA[fm], bv, acc[fm][fn], 0, 0, 0);
      }
      if (t < ct)
#pragma unroll
        for (int fm = 0; fm < 4; ++fm) afA[fm] = ldA(fm, t + 1, 0);
#pragma unroll
      for (int fn = 0; fn < 4; ++fn) {
        bf16x8 bv = *(const bf16x8*)(&B_all[boff[fn] + ks + 32]);
#pragma unroll
        for (int fm = 0; fm < 4; ++fm)
          acc[fm][fn] = MFMA_BF16(afB[fm], bv, acc[fm][fn], 0, 0, 0);
      }
      if (t == ct) break;
#pragma unroll
      for (int fm = 0; fm < 4; ++fm) afB[fm] = ldA(fm, t + 1, 1);
    }
  } else {
    for (int t = 0; t <= ct; ++t) {
      const int ks = t * 128 + g * 64;
#pragma unroll
      for (int kk = 0; kk < 2; ++kk) {
        bf16x8 af[4];
#pragma unroll
        for (int fm = 0; fm < 4; ++fm) af[fm] = ldAc(fm, t, kk);
#pragma unroll
        for (int fn = 0; fn < 4; ++fn) {
          bf16x8 bv = *(const bf16x8*)(&B_all[boff[fn] + ks + kk * 32]);
#pragma unroll
          for (int fm = 0; fm < 4; ++fm)
            acc[fm][fn] = MFMA_BF16(af[fm], bv, acc[fm][fn], 0, 0, 0);
        }
      }
    }
  }

  // combine: group1's partials -> group0 via LDS (2 rounds of 2 fm each)
  const int j = tid & 255;
  for (int r = 0; r < 2; ++r) {
    __syncthreads();                       // (r=0: also fences last B reads)
    if (g == 1) {
      for (int fm2 = 0; fm2 < 2; ++fm2)
        for (int fn = 0; fn < 4; ++fn)
          ep[j * 9 + fm2 * 4 + fn] = acc[r * 2 + fm2][fn];
    }
    __syncthreads();
    if (g == 0) {
      for (int fm2 = 0; fm2 < 2; ++fm2)
        for (int fn = 0; fn < 4; ++fn)
          acc[r * 2 + fm2][fn] += ep[j * 9 + fm2 * 4 + fn];
    }
  }

  // epilogue (group 0 only): C/D layout col=lane&15, row=quad*4+r
  if (g == 0) {
    for (int fm = 0; fm < 4; ++fm) {
      int row_base = m0 + wm * 64 + fm * 16 + quad * 4;
      for (int fn = 0; fn < 4; ++fn) {
        int col = n0 + wn * 64 + fn * 16 + lane16;
        for (int r = 0; r < 4; ++r)
          out[(size_t)(row_base + r) * NDIM + col] = acc[fm][fn][r];
      }
    }
  }
}

extern "C" void kernel_launch(void* const* d_in, const int* in_sizes, int n_in,
                              void* d_out, int out_size, void* d_ws, size_t ws_size,
                              hipStream_t stream) {
  const float* x    = (const float*)d_in[0];
  const float* kern = (const float*)d_in[1];
  float* out = (float*)d_out;

  u16* krevs = (u16*)d_ws;
  u16* xb    = (u16*)((char*)d_ws + KREV_BYTES);
  const size_t need_fast = (size_t)KREV_BYTES + (size_t)MDIM * KDIM * 2;

  if (ws_size >= need_fast) {
    prep<<<4096 + 18, 256, 0, stream>>>(x, kern, xb, krevs, 4096);
    toeplitz_gemm<false><<<512, 512, 0, stream>>>(xb, krevs, out);
  } else {
    prep<<<18, 256, 0, stream>>>(x, kern, xb, krevs, 0);
    toeplitz_gemm<true><<<512, 512, 0, stream>>>(x, krevs, out);
  }
}

// Round 8
// 112.802 us; speedup vs baseline: 1.1081x; 1.0369x over previous
//
#include <hip/hip_runtime.h>
#include <hip/hip_bf16.h>

// out[b,i] = sum_{j<=i} x[b,j] * kernel[i-j]   (causal Toeplitz matmul)
// M=2048, N=K=4096. f32 in/out, bf16 MFMA compute.
//
// R13: uniform blocks via in-block ct-pairing. R12 (barrier-free) reached
// ~39us but the causal triangle leaves a tail: CU pair (31,0) runs 32 steps
// at half occupancy (OccupancyPercent ~23% = idle-tail signature); with
// latency-leaning self-paced steps, makespan ~ max-block not sum. Now each
// block = one 64-row m-tile x column tiles {31-ctp, ctp} run SEQUENTIALLY
// (big first): every block exactly 33 K-steps -> 512 identical blocks, 2/CU,
// 16 waves sustained, zero tail. B windows complement to a constant 4544
// elems/copy -> LDS 73984 B fixed (2 blocks = 148KB <= 160KB); phase-1's B
// region (>=38KB, dead after phase 1) hosts the 36.8KB combine overlay while
// phase-2's window stays intact. Waves per group: 2wm x 2wn over 64x128,
// acc[2][4] (~85 VGPR, 4 w/SIMD). Accepted cost: B-port doubles (64-row
// blocks), expect bank-conflict counter ~2x; A traffic unchanged and both
// co-resident blocks now share the SAME A panel (L2+L1 friendly).

typedef unsigned short u16;
typedef __attribute__((ext_vector_type(8))) short  bf16x8;
typedef __attribute__((ext_vector_type(8))) unsigned short u16x8;
typedef __attribute__((ext_vector_type(4))) float  f32x4;

#define KDIM 4096
#define NDIM 4096
#define MDIM 2048
#define KREV_STRIDE 4608                    // elems per shifted copy (global)
#define KREV_BYTES  (8 * KREV_STRIDE * 2)   // 73728

#define MFMA_BF16 __builtin_amdgcn_mfma_f32_16x16x32_bf16

static __device__ inline u16 f2bf(float f) {
  unsigned u = __builtin_bit_cast(unsigned, f);
  unsigned r = u + 0x7FFFu + ((u >> 16) & 1u);
  return (u16)(r >> 16);
}

static __device__ inline void async_copy16(const void* g, void* l) {
  __builtin_amdgcn_global_load_lds((const __attribute__((address_space(1))) void*)g,
                                   (__attribute__((address_space(3))) void*)l,
                                   16, 0, 0);
}

// Fused prep: blocks [0, conv_blocks) convert x->bf16 into the fragment-tiled
// layout; last 18 blocks build 8 shifted krev copies.
// Tiled layout: elem index = (rg*128 + kb)*512 + l*8 + e, where the 8 elems e
// are x[row = rg*16 + (l&15)][k = kb*32 + (l>>4)*8 + e]. One wave's fragment
// load (fixed rg,kb; l=lane) is 1KB contiguous.
__global__ __launch_bounds__(256) void prep(const float* __restrict__ x,
                                            const float* __restrict__ kern,
                                            u16* __restrict__ xb,
                                            u16* __restrict__ krevs,
                                            int conv_blocks) {
  int kblk = (int)blockIdx.x - conv_blocks;
  if (kblk >= 0) {
    int u = kblk * 256 + threadIdx.x;
    for (int a = 0; a < 8; ++a) {
      int t = u + a - 8;
      u16 v = 0;
      if (t >= 0 && t <= 4095) v = f2bf(kern[4095 - t]);
      krevs[a * KREV_STRIDE + u] = v;
    }
  } else {
    unsigned tg  = blockIdx.x * 256 + threadIdx.x;   // 0..2048*4096/8-1
    unsigned l   = tg & 63;
    unsigned kb  = (tg >> 6) & 127;
    unsigned rg  = tg >> 13;                         // 0..127
    unsigned row = rg * 16 + (l & 15);
    unsigned k   = kb * 32 + (l >> 4) * 8;
    const f32x4* p = (const f32x4*)(x + (size_t)row * KDIM + k);
    f32x4 v0 = p[0], v1 = p[1];
    u16x8 r;
    r[0] = f2bf(v0[0]); r[1] = f2bf(v0[1]); r[2] = f2bf(v0[2]); r[3] = f2bf(v0[3]);
    r[4] = f2bf(v1[0]); r[5] = f2bf(v1[1]); r[6] = f2bf(v1[2]); r[7] = f2bf(v1[3]);
    *(u16x8*)(xb + (size_t)tg * 8) = r;              // coalesced 1KB/wave
  }
}

template <bool CONV>
__global__ __launch_bounds__(512, 4) void toeplitz_gemm(const void* __restrict__ Av,
                                                        const u16* __restrict__ krevs,
                                                        float* __restrict__ out) {
  // LDS: two B windows, 8 copies each. len1+len2 = 128*33+320 = 4544 elems;
  // len == 32 (mod 64) always -> stride = len+40 (== 8 mod 64, bank phase
  // preserved); stride1+stride2 = 4624 const -> 8*4624*2 = 73984 B fixed.
  // Phase-1 region ([0, 8*stride1*2) >= 38016 B) hosts the 36864 B epilogue
  // overlay after phase 1; phase-2 region stays intact.
  __shared__ __align__(16) char smem_raw[73984];
  u16*   B_all = (u16*)smem_raw;
  f32x4* ep    = (f32x4*)smem_raw;            // combine overlay, 9 f32x4 per slot

  const int tid  = threadIdx.x;
  const int w    = tid >> 6;        // 0..7
  const int g    = w >> 2;          // K-group 0..1
  const int wl   = w & 3;           // wave-in-group
  const int lane = tid & 63;
  const int lane16 = lane & 15;
  const int quad   = lane >> 4;
  const int wm = wl >> 1;           // 32-row half
  const int wn = wl & 1;            // 64-col half

  // XCD-affine uniform mapping: XCD x_=b&7 owns full panels {x_, x_+8};
  // mt2 = 64-row tile, ctp picks the pair {31-ctp, ctp}. Co-resident pair
  // (b, b+256) shares the SAME mt2 (ctp differs by 8). All blocks: 33 steps.
  const int b   = (int)blockIdx.x;
  const int x_  = b & 7;
  const int jj  = b >> 3;                 // 0..63 within XCD
  const int p_  = x_ + 8 * (jj & 1);      // full panel 0..15
  const int mt2 = p_ * 2 + ((jj >> 1) & 1); // 64-row tile 0..31
  const int ctp = jj >> 2;                // 0..15
  const int ct1 = 31 - ctp;               // phase 1 (big, >=16)
  const int ct2 = ctp;                    // phase 2
  const int m0  = mt2 * 64;

  const int len1 = 128 * (ct1 + 1) + 160, stride1 = len1 + 40;
  const int len2 = 128 * (ct2 + 1) + 160, stride2 = len2 + 40;
  const int base2 = 8 * stride1;          // elems
  const int W1 = 3968 - 128 * ct1;
  const int W2 = 3968 - 128 * ct2;

  // A addressing (R11/R12): SGPR-ized; elem(fm,t,kk) =
  // (mt2*4 + wm*2 + fm)*65536 + g*1024 + t*2048 + kk*512 + lane*8.
  const int wmu = __builtin_amdgcn_readfirstlane(wm);
  const int gu  = __builtin_amdgcn_readfirstlane(g);
  const u16*   xb2 = (const u16*)Av;
  const float* xf  = (const float*)Av;
  int aoffs[2];
  for (int fm = 0; fm < 2; ++fm)
    aoffs[fm] = (mt2 * 4 + wmu * 2 + fm) * 65536 + gu * 1024 + lane * 8;
  const int rowb = m0 + wm * 32 + lane16;   // CONV source row base

  auto ldA = [&](int fm, int t, int kk) -> bf16x8 {
    return *(const bf16x8*)(xb2 + aoffs[fm] + t * 2048 + kk * 512);
  };
  auto ldAc = [&](int fm, int t, int kk) -> bf16x8 {
    const float* px = xf + (size_t)(rowb + fm * 16) * KDIM +
                      t * 128 + gu * 64 + kk * 32 + quad * 8;
    f32x4 v0 = *(const f32x4*)px, v1 = *(const f32x4*)(px + 4);
    u16x8 r;
    r[0]=f2bf(v0[0]); r[1]=f2bf(v0[1]); r[2]=f2bf(v0[2]); r[3]=f2bf(v0[3]);
    r[4]=f2bf(v1[0]); r[5]=f2bf(v1[1]); r[6]=f2bf(v1[2]); r[7]=f2bf(v1[3]);
    return __builtin_bit_cast(bf16x8, r);
  };

  // ---- prologue: stage BOTH B windows (wave w stages copy w) ----
  auto stageWin = [&](int base_e, int stride_e, int len_e, int Wp) {
    const u16* src = krevs + w * KREV_STRIDE + Wp;
    char* dstb = smem_raw + (size_t)(base_e + w * stride_e) * 2;
    for (int c = 0; c * 512 < len_e; ++c) {
      int idx = c * 512 + lane * 8;
      if (idx < len_e)
        async_copy16(src + idx, dstb + (size_t)c * 1024);
    }
  };
  stageWin(0, stride1, len1, W1);
  stageWin(base2, stride2, len2, W2);
  asm volatile("s_waitcnt vmcnt(0)" ::: "memory");
  __builtin_amdgcn_s_barrier();
  asm volatile("" ::: "memory");

  // ---- one phase: barrier-free K loop + combine + epilogue ----
  auto runPhase = [&](int ctq, int base_e, int stride_q, int Wq) {
    const int n0q = ctq * 128;
    int boff[4];
    for (int fn = 0; fn < 4; ++fn) {
      int n_g = n0q + wn * 64 + fn * 16 + lane16;
      int s0  = 4095 - n_g + quad * 8;
      int a   = s0 & 7;
      boff[fn] = base_e + a * stride_q + (s0 - a + 8 - Wq);
    }
    f32x4 acc[2][4] = {};

    if constexpr (!CONV) {
      bf16x8 afA[2], afB[2];
#pragma unroll
      for (int fm = 0; fm < 2; ++fm) afA[fm] = ldA(fm, 0, 0);
#pragma unroll
      for (int fm = 0; fm < 2; ++fm) afB[fm] = ldA(fm, 0, 1);
      for (int t = 0; ; ++t) {
        const int ks = t * 128 + g * 64;
#pragma unroll
        for (int fn = 0; fn < 4; ++fn) {
          bf16x8 bv = *(const bf16x8*)(&B_all[boff[fn] + ks]);
#pragma unroll
          for (int fm = 0; fm < 2; ++fm)
            acc[fm][fn] = MFMA_BF16(afA[fm], bv, acc[fm][fn], 0, 0, 0);
        }
        if (t < ctq)
#pragma unroll
          for (int fm = 0; fm < 2; ++fm) afA[fm] = ldA(fm, t + 1, 0);
#pragma unroll
        for (int fn = 0; fn < 4; ++fn) {
          bf16x8 bv = *(const bf16x8*)(&B_all[boff[fn] + ks + 32]);
#pragma unroll
          for (int fm = 0; fm < 2; ++fm)
            acc[fm][fn] = MFMA_BF16(afB[fm], bv, acc[fm][fn], 0, 0, 0);
        }
        if (t == ctq) break;
#pragma unroll
        for (int fm = 0; fm < 2; ++fm) afB[fm] = ldA(fm, t + 1, 1);
      }
    } else {
      for (int t = 0; t <= ctq; ++t) {
        const int ks = t * 128 + g * 64;
#pragma unroll
        for (int kk = 0; kk < 2; ++kk) {
          bf16x8 af[2];
#pragma unroll
          for (int fm = 0; fm < 2; ++fm) af[fm] = ldAc(fm, t, kk);
#pragma unroll
          for (int fn = 0; fn < 4; ++fn) {
            bf16x8 bv = *(const bf16x8*)(&B_all[boff[fn] + ks + kk * 32]);
#pragma unroll
            for (int fm = 0; fm < 2; ++fm)
              acc[fm][fn] = MFMA_BF16(af[fm], bv, acc[fm][fn], 0, 0, 0);
          }
        }
      }
    }

    // combine: group1 -> group0 via LDS overlay (phase-1 B region, now dead)
    const int j = tid & 255;
    __syncthreads();                       // all compute on this phase done
    if (g == 1) {
      for (int fm = 0; fm < 2; ++fm)
        for (int fn = 0; fn < 4; ++fn)
          ep[j * 9 + fm * 4 + fn] = acc[fm][fn];
    }
    __syncthreads();
    if (g == 0) {
      for (int fm = 0; fm < 2; ++fm)
        for (int fn = 0; fn < 4; ++fn) {
          f32x4 v = acc[fm][fn];
          f32x4 o = ep[j * 9 + fm * 4 + fn];
          v[0] += o[0]; v[1] += o[1]; v[2] += o[2]; v[3] += o[3];
          int row_base = m0 + wm * 32 + fm * 16 + quad * 4;
          int col = n0q + wn * 64 + fn * 16 + lane16;
          for (int r = 0; r < 4; ++r)
            out[(size_t)(row_base + r) * NDIM + col] = v[r];
        }
    }
  };

  runPhase(ct1, 0, stride1, W1);       // big phase first (region >= 38KB)
  runPhase(ct2, base2, stride2, W2);   // its window untouched by the overlay
}

extern "C" void kernel_launch(void* const* d_in, const int* in_sizes, int n_in,
                              void* d_out, int out_size, void* d_ws, size_t ws_size,
                              hipStream_t stream) {
  const float* x    = (const float*)d_in[0];
  const float* kern = (const float*)d_in[1];
  float* out = (float*)d_out;

  u16* krevs = (u16*)d_ws;
  u16* xb    = (u16*)((char*)d_ws + KREV_BYTES);
  const size_t need_fast = (size_t)KREV_BYTES + (size_t)MDIM * KDIM * 2;

  if (ws_size >= need_fast) {
    prep<<<4096 + 18, 256, 0, stream>>>(x, kern, xb, krevs, 4096);
    toeplitz_gemm<false><<<512, 512, 0, stream>>>(xb, krevs, out);
  } else {
    prep<<<18, 256, 0, stream>>>(x, kern, xb, krevs, 0);
    toeplitz_gemm<true><<<512, 512, 0, stream>>>(x, krevs, out);
  }
}

// Round 9
// 112.485 us; speedup vs baseline: 1.1112x; 1.0028x over previous
//
#include <hip/hip_runtime.h>
#include <hip/hip_bf16.h>

// out[b,i] = sum_{j<=i} x[b,j] * kernel[i-j]   (causal Toeplitz matmul)
// M=2048, N=K=4096. f32 in/out, bf16 MFMA compute.
//
// R14: B-read software pipelining. R13 (uniform 33-step blocks, ~35us gemm)
// left both pipes half-idle (matrix 49%, port 60%): each wave issued its 4
// B-frag ds_reads JIT and ate ~120cyc lgkm latency before every 8-MFMA
// cluster; 4 waves/SIMD don't cover the bubble. B LDS is read-only with zero
// barriers since R12, so reads may float arbitrarily ahead. Now bvA/bvB
// double-buffered register sets: the 4 reads for kk+1 issue BEFORE the MFMAs
// consuming kk -> every wave keeps 4 reads in flight behind ~310 SIMD-cyc of
// MFMA work; port streams continuously. VGPR ~100 (<=128, occupancy
// unchanged). A prefetch stays 1 step ahead. Mapping/whole-window B/two-phase
// structure from R13 unchanged.

typedef unsigned short u16;
typedef __attribute__((ext_vector_type(8))) short  bf16x8;
typedef __attribute__((ext_vector_type(8))) unsigned short u16x8;
typedef __attribute__((ext_vector_type(4))) float  f32x4;

#define KDIM 4096
#define NDIM 4096
#define MDIM 2048
#define KREV_STRIDE 4608                    // elems per shifted copy (global)
#define KREV_BYTES  (8 * KREV_STRIDE * 2)   // 73728

#define MFMA_BF16 __builtin_amdgcn_mfma_f32_16x16x32_bf16

static __device__ inline u16 f2bf(float f) {
  unsigned u = __builtin_bit_cast(unsigned, f);
  unsigned r = u + 0x7FFFu + ((u >> 16) & 1u);
  return (u16)(r >> 16);
}

static __device__ inline void async_copy16(const void* g, void* l) {
  __builtin_amdgcn_global_load_lds((const __attribute__((address_space(1))) void*)g,
                                   (__attribute__((address_space(3))) void*)l,
                                   16, 0, 0);
}

// Fused prep: blocks [0, conv_blocks) convert x->bf16 into the fragment-tiled
// layout; last 18 blocks build 8 shifted krev copies.
// Tiled layout: elem index = (rg*128 + kb)*512 + l*8 + e, where the 8 elems e
// are x[row = rg*16 + (l&15)][k = kb*32 + (l>>4)*8 + e]. One wave's fragment
// load (fixed rg,kb; l=lane) is 1KB contiguous.
__global__ __launch_bounds__(256) void prep(const float* __restrict__ x,
                                            const float* __restrict__ kern,
                                            u16* __restrict__ xb,
                                            u16* __restrict__ krevs,
                                            int conv_blocks) {
  int kblk = (int)blockIdx.x - conv_blocks;
  if (kblk >= 0) {
    int u = kblk * 256 + threadIdx.x;
    for (int a = 0; a < 8; ++a) {
      int t = u + a - 8;
      u16 v = 0;
      if (t >= 0 && t <= 4095) v = f2bf(kern[4095 - t]);
      krevs[a * KREV_STRIDE + u] = v;
    }
  } else {
    unsigned tg  = blockIdx.x * 256 + threadIdx.x;   // 0..2048*4096/8-1
    unsigned l   = tg & 63;
    unsigned kb  = (tg >> 6) & 127;
    unsigned rg  = tg >> 13;                         // 0..127
    unsigned row = rg * 16 + (l & 15);
    unsigned k   = kb * 32 + (l >> 4) * 8;
    const f32x4* p = (const f32x4*)(x + (size_t)row * KDIM + k);
    f32x4 v0 = p[0], v1 = p[1];
    u16x8 r;
    r[0] = f2bf(v0[0]); r[1] = f2bf(v0[1]); r[2] = f2bf(v0[2]); r[3] = f2bf(v0[3]);
    r[4] = f2bf(v1[0]); r[5] = f2bf(v1[1]); r[6] = f2bf(v1[2]); r[7] = f2bf(v1[3]);
    *(u16x8*)(xb + (size_t)tg * 8) = r;              // coalesced 1KB/wave
  }
}

template <bool CONV>
__global__ __launch_bounds__(512, 4) void toeplitz_gemm(const void* __restrict__ Av,
                                                        const u16* __restrict__ krevs,
                                                        float* __restrict__ out) {
  // LDS: two B windows, 8 copies each. len1+len2 = 128*33+320 = 4544 elems;
  // stride = len+40 (== 8 mod 64); stride1+stride2 = 4624 const -> 73984 B.
  // Phase-1 region (>= 38016 B, dead after phase 1) hosts the 36864 B
  // combine overlay; phase-2 region stays intact.
  __shared__ __align__(16) char smem_raw[73984];
  u16*   B_all = (u16*)smem_raw;
  f32x4* ep    = (f32x4*)smem_raw;            // combine overlay, 9 f32x4 per slot

  const int tid  = threadIdx.x;
  const int w    = tid >> 6;        // 0..7
  const int g    = w >> 2;          // K-group 0..1
  const int wl   = w & 3;           // wave-in-group
  const int lane = tid & 63;
  const int lane16 = lane & 15;
  const int quad   = lane >> 4;
  const int wm = wl >> 1;           // 32-row half
  const int wn = wl & 1;            // 64-col half

  // XCD-affine uniform mapping (R13): XCD x_=b&7 owns panels {x_, x_+8};
  // every block = one 64-row tile x column pair {31-ctp, ctp} = 33 K-steps.
  const int b   = (int)blockIdx.x;
  const int x_  = b & 7;
  const int jj  = b >> 3;                 // 0..63 within XCD
  const int p_  = x_ + 8 * (jj & 1);      // full panel 0..15
  const int mt2 = p_ * 2 + ((jj >> 1) & 1); // 64-row tile 0..31
  const int ctp = jj >> 2;                // 0..15
  const int ct1 = 31 - ctp;               // phase 1 (big, >=16)
  const int ct2 = ctp;                    // phase 2
  const int m0  = mt2 * 64;

  const int len1 = 128 * (ct1 + 1) + 160, stride1 = len1 + 40;
  const int len2 = 128 * (ct2 + 1) + 160, stride2 = len2 + 40;
  const int base2 = 8 * stride1;          // elems
  const int W1 = 3968 - 128 * ct1;
  const int W2 = 3968 - 128 * ct2;

  // A addressing (R11): SGPR-ized; elem(fm,t,kk) =
  // (mt2*4 + wm*2 + fm)*65536 + g*1024 + t*2048 + kk*512 + lane*8.
  const int wmu = __builtin_amdgcn_readfirstlane(wm);
  const int gu  = __builtin_amdgcn_readfirstlane(g);
  const u16*   xb2 = (const u16*)Av;
  const float* xf  = (const float*)Av;
  int aoffs[2];
  for (int fm = 0; fm < 2; ++fm)
    aoffs[fm] = (mt2 * 4 + wmu * 2 + fm) * 65536 + gu * 1024 + lane * 8;
  const int rowb = m0 + wm * 32 + lane16;   // CONV source row base

  auto ldA = [&](int fm, int t, int kk) -> bf16x8 {
    return *(const bf16x8*)(xb2 + aoffs[fm] + t * 2048 + kk * 512);
  };
  auto ldAc = [&](int fm, int t, int kk) -> bf16x8 {
    const float* px = xf + (size_t)(rowb + fm * 16) * KDIM +
                      t * 128 + gu * 64 + kk * 32 + quad * 8;
    f32x4 v0 = *(const f32x4*)px, v1 = *(const f32x4*)(px + 4);
    u16x8 r;
    r[0]=f2bf(v0[0]); r[1]=f2bf(v0[1]); r[2]=f2bf(v0[2]); r[3]=f2bf(v0[3]);
    r[4]=f2bf(v1[0]); r[5]=f2bf(v1[1]); r[6]=f2bf(v1[2]); r[7]=f2bf(v1[3]);
    return __builtin_bit_cast(bf16x8, r);
  };

  // ---- prologue: stage BOTH B windows (wave w stages copy w) ----
  auto stageWin = [&](int base_e, int stride_e, int len_e, int Wp) {
    const u16* src = krevs + w * KREV_STRIDE + Wp;
    char* dstb = smem_raw + (size_t)(base_e + w * stride_e) * 2;
    for (int c = 0; c * 512 < len_e; ++c) {
      int idx = c * 512 + lane * 8;
      if (idx < len_e)
        async_copy16(src + idx, dstb + (size_t)c * 1024);
    }
  };
  stageWin(0, stride1, len1, W1);
  stageWin(base2, stride2, len2, W2);
  asm volatile("s_waitcnt vmcnt(0)" ::: "memory");
  __builtin_amdgcn_s_barrier();
  asm volatile("" ::: "memory");

  // ---- one phase: barrier-free, B-reads pipelined one kk ahead ----
  auto runPhase = [&](int ctq, int base_e, int stride_q, int Wq) {
    const int n0q = ctq * 128;
    int boff[4];
    for (int fn = 0; fn < 4; ++fn) {
      int n_g = n0q + wn * 64 + fn * 16 + lane16;
      int s0  = 4095 - n_g + quad * 8;
      int a   = s0 & 7;
      boff[fn] = base_e + a * stride_q + (s0 - a + 8 - Wq);
    }
    f32x4 acc[2][4] = {};

    if constexpr (!CONV) {
      bf16x8 afA[2], afB[2], bvA[4], bvB[4];
#pragma unroll
      for (int fm = 0; fm < 2; ++fm) afA[fm] = ldA(fm, 0, 0);
#pragma unroll
      for (int fm = 0; fm < 2; ++fm) afB[fm] = ldA(fm, 0, 1);
#pragma unroll
      for (int fn = 0; fn < 4; ++fn)
        bvA[fn] = *(const bf16x8*)(&B_all[boff[fn] + g * 64]);   // t=0, kk=0
      for (int t = 0; ; ++t) {
        const int ks = t * 128 + g * 64;
        // kk=0: prefetch bvB (kk=1), consume bvA
#pragma unroll
        for (int fn = 0; fn < 4; ++fn)
          bvB[fn] = *(const bf16x8*)(&B_all[boff[fn] + ks + 32]);
#pragma unroll
        for (int fn = 0; fn < 4; ++fn)
#pragma unroll
          for (int fm = 0; fm < 2; ++fm)
            acc[fm][fn] = MFMA_BF16(afA[fm], bvA[fn], acc[fm][fn], 0, 0, 0);
        if (t < ctq)
#pragma unroll
          for (int fm = 0; fm < 2; ++fm) afA[fm] = ldA(fm, t + 1, 0);
        // kk=1: prefetch bvA (t+1, kk=0), consume bvB
        if (t < ctq)
#pragma unroll
          for (int fn = 0; fn < 4; ++fn)
            bvA[fn] = *(const bf16x8*)(&B_all[boff[fn] + ks + 128]);
#pragma unroll
        for (int fn = 0; fn < 4; ++fn)
#pragma unroll
          for (int fm = 0; fm < 2; ++fm)
            acc[fm][fn] = MFMA_BF16(afB[fm], bvB[fn], acc[fm][fn], 0, 0, 0);
        if (t == ctq) break;
#pragma unroll
        for (int fm = 0; fm < 2; ++fm) afB[fm] = ldA(fm, t + 1, 1);
      }
    } else {
      for (int t = 0; t <= ctq; ++t) {
        const int ks = t * 128 + g * 64;
#pragma unroll
        for (int kk = 0; kk < 2; ++kk) {
          bf16x8 af[2];
#pragma unroll
          for (int fm = 0; fm < 2; ++fm) af[fm] = ldAc(fm, t, kk);
#pragma unroll
          for (int fn = 0; fn < 4; ++fn) {
            bf16x8 bv = *(const bf16x8*)(&B_all[boff[fn] + ks + kk * 32]);
#pragma unroll
            for (int fm = 0; fm < 2; ++fm)
              acc[fm][fn] = MFMA_BF16(af[fm], bv, acc[fm][fn], 0, 0, 0);
          }
        }
      }
    }

    // combine: group1 -> group0 via LDS overlay (phase-1 B region, now dead)
    const int j = tid & 255;
    __syncthreads();                       // all compute on this phase done
    if (g == 1) {
      for (int fm = 0; fm < 2; ++fm)
        for (int fn = 0; fn < 4; ++fn)
          ep[j * 9 + fm * 4 + fn] = acc[fm][fn];
    }
    __syncthreads();
    if (g == 0) {
      for (int fm = 0; fm < 2; ++fm)
        for (int fn = 0; fn < 4; ++fn) {
          f32x4 v = acc[fm][fn];
          f32x4 o = ep[j * 9 + fm * 4 + fn];
          v[0] += o[0]; v[1] += o[1]; v[2] += o[2]; v[3] += o[3];
          int row_base = m0 + wm * 32 + fm * 16 + quad * 4;
          int col = n0q + wn * 64 + fn * 16 + lane16;
          for (int r = 0; r < 4; ++r)
            out[(size_t)(row_base + r) * NDIM + col] = v[r];
        }
    }
  };

  runPhase(ct1, 0, stride1, W1);       // big phase first (region >= 38KB)
  runPhase(ct2, base2, stride2, W2);   // its window untouched by the overlay
}

extern "C" void kernel_launch(void* const* d_in, const int* in_sizes, int n_in,
                              void* d_out, int out_size, void* d_ws, size_t ws_size,
                              hipStream_t stream) {
  const float* x    = (const float*)d_in[0];
  const float* kern = (const float*)d_in[1];
  float* out = (float*)d_out;

  u16* krevs = (u16*)d_ws;
  u16* xb    = (u16*)((char*)d_ws + KREV_BYTES);
  const size_t need_fast = (size_t)KREV_BYTES + (size_t)MDIM * KDIM * 2;

  if (ws_size >= need_fast) {
    prep<<<4096 + 18, 256, 0, stream>>>(x, kern, xb, krevs, 4096);
    toeplitz_gemm<false><<<512, 512, 0, stream>>>(xb, krevs, out);
  } else {
    prep<<<18, 256, 0, stream>>>(x, kern, xb, krevs, 0);
    toeplitz_gemm<true><<<512, 512, 0, stream>>>(x, krevs, out);
  }
}